// Round 2
// baseline (940.012 us; speedup 1.0000x reference)
//
#include <hip/hip_runtime.h>

#define T_TOK 2048
#define H_DIM 1024
#define E_NUM 64
#define TOPK  6
#define I_DIM 512
#define SI_DIM 1024
#define CAP   512   // max tokens per expert supported (avg 192)

typedef __attribute__((ext_vector_type(8))) short bf16x8;
typedef __attribute__((ext_vector_type(4))) float f32x4;
typedef __attribute__((ext_vector_type(4))) short short4v;

__device__ __forceinline__ short f2bf(float f) {
  union { float f; unsigned u; } v; v.f = f;
  unsigned r = v.u + 0x7FFFu + ((v.u >> 16) & 1u);  // RNE
  return (short)(r >> 16);
}

// ---------------- x -> bf16 (no transpose; A operand is K-contiguous) ----------------
__global__ __launch_bounds__(256) void cvt_kernel(const float* __restrict__ x,
                                                  short* __restrict__ xb) {
  int i = (blockIdx.x * 256 + threadIdx.x) * 4;
  float4 v = *(const float4*)(x + i);
  short4v o;
  o[0] = f2bf(v.x); o[1] = f2bf(v.y); o[2] = f2bf(v.z); o[3] = f2bf(v.w);
  *(short4v*)(xb + i) = o;
}

// ---------------- weight convert + transpose: fp32 [R,C] -> bf16 [C,R] ----------------
// 32x32 tile, 256 threads (4 elems/thread). Coalesced float4 read, short4 write.
__global__ __launch_bounds__(256) void tr_kernel(const float* __restrict__ in,
                                                 short* __restrict__ outp,
                                                 int R, int C) {
  __shared__ short lds[32][36];   // 36 shorts = 72B row: keeps short4 stores 8B-aligned
  const size_t off = (size_t)blockIdx.z * R * C;
  const int c0 = blockIdx.x * 32, r0 = blockIdx.y * 32;
  const int tr = threadIdx.x >> 3;         // 0..31
  const int tc = (threadIdx.x & 7) * 4;    // 0,4,..,28
  float4 v = *(const float4*)(in + off + (size_t)(r0 + tr) * C + c0 + tc);
  short4v s;
  s[0] = f2bf(v.x); s[1] = f2bf(v.y); s[2] = f2bf(v.z); s[3] = f2bf(v.w);
  *(short4v*)&lds[tr][tc] = s;
  __syncthreads();
  short4v o;
  #pragma unroll
  for (int j = 0; j < 4; j++) o[j] = lds[tc + j][tr];
  // out[c][r] = in[r][c]
  *(short4v*)(outp + off + (size_t)(c0 + tr) * R + r0 + tc) = o;
}

__global__ void zero_cnt(int* __restrict__ cnt) {
  if (threadIdx.x < E_NUM) cnt[threadIdx.x] = 0;
}

// ---------------- router: scores = sigmoid(x @ gate_w^T), exact fp32 ----------------
__global__ __launch_bounds__(256) void router_kernel(const float* __restrict__ x,
                                                     const float* __restrict__ gw,
                                                     float* __restrict__ scores) {
  int t = blockIdx.x * 4 + (threadIdx.x >> 6);
  int e = threadIdx.x & 63;
  const float4* xr = (const float4*)(x + (size_t)t * H_DIM);
  const float4* wr = (const float4*)(gw + (size_t)e * H_DIM);
  float s = 0.f;
  #pragma unroll 4
  for (int i = 0; i < H_DIM / 4; i++) {
    float4 a = xr[i], b = wr[i];
    s = fmaf(a.x, b.x, s); s = fmaf(a.y, b.y, s);
    s = fmaf(a.z, b.z, s); s = fmaf(a.w, b.w, s);
  }
  scores[t * E_NUM + e] = 1.f / (1.f + __expf(-s));
}

// ---------------- top-k per token, build per-expert token lists ----------------
__global__ __launch_bounds__(64) void topk_kernel(const float* __restrict__ scores,
                                                  const float* __restrict__ bias,
                                                  int* __restrict__ cnt,
                                                  int* __restrict__ tokens,
                                                  float* __restrict__ wts) {
  int t = blockIdx.x;
  int e = threadIdx.x;
  float s = scores[t * E_NUM + e];
  float c = s + bias[e];
  int selected = 0;
  float sum = 0.f;
  for (int k = 0; k < TOPK; k++) {
    float v = c; int idx = e;
    #pragma unroll
    for (int off = 32; off > 0; off >>= 1) {
      float v2 = __shfl_xor(v, off);
      int  i2 = __shfl_xor(idx, off);
      if (v2 > v || (v2 == v && i2 < idx)) { v = v2; idx = i2; }
    }
    sum += __shfl(s, idx);
    if (e == idx) { selected = 1; c = -__builtin_inff(); }
  }
  if (selected) {
    int pos = atomicAdd(&cnt[e], 1);
    if (pos < CAP) {
      tokens[e * CAP + pos] = t;
      wts[e * CAP + pos] = s / sum;
    }
  }
}

// ---------------- fused gate+up GEMM + SwiGLU (+routing weight) ----------------
// All operands bf16, both K-contiguous: A=[M,K], B=[N,K] (pre-transposed).
// Block: 4 waves. Tile M=64, N=128 (32 cols/wave), K-step 32.
template<int MOE>
__global__ __launch_bounds__(256) void gu_kernel(
    const short* __restrict__ Xb, const short* __restrict__ WgT,
    const short* __restrict__ WuT, short* __restrict__ Out,
    const int* __restrict__ tokens, const float* __restrict__ wts,
    const int* __restrict__ cnt, int Kd, int Nd, int outLd)
{
  const int e  = blockIdx.z;
  const int m0 = blockIdx.y * 64;
  const int n0 = blockIdx.x * 128;
  int count = 1 << 30;
  const int* tlist = tokens;
  const float* wlist = wts;
  if (MOE) {
    int c = cnt[e]; if (c > CAP) c = CAP;
    count = c;
    if (m0 >= count) return;
    tlist = tokens + e * CAP;
    wlist = wts + e * CAP;
  }
  const int lane = threadIdx.x & 63;
  const int wave = threadIdx.x >> 6;
  const int quad = lane >> 4;
  const int l16  = lane & 15;
  const int ncol = n0 + wave * 32;

  const size_t wOff = MOE ? (size_t)e * Kd * Nd : 0;
  const short* wg0 = WgT + wOff + (size_t)(ncol + l16) * Kd + quad * 8;
  const short* wu0 = WuT + wOff + (size_t)(ncol + l16) * Kd + quad * 8;

  const short* arow[4];
  #pragma unroll
  for (int mt = 0; mt < 4; mt++) {
    int gr = m0 + mt * 16 + l16;
    int trow;
    if (MOE) trow = (gr < count) ? tlist[gr] : tlist[0];
    else     trow = gr;
    arow[mt] = Xb + (size_t)trow * Kd + quad * 8;
  }

  f32x4 accg[2][4], accu[2][4];
  #pragma unroll
  for (int i = 0; i < 2; i++)
    #pragma unroll
    for (int j = 0; j < 4; j++) {
      accg[i][j] = (f32x4){0.f, 0.f, 0.f, 0.f};
      accu[i][j] = (f32x4){0.f, 0.f, 0.f, 0.f};
    }

  const int kSteps = Kd >> 5;
  for (int kb = 0; kb < kSteps; kb++) {
    const int ko = kb * 32;
    bf16x8 a[4];
    #pragma unroll
    for (int mt = 0; mt < 4; mt++)
      a[mt] = *(const bf16x8*)(arow[mt] + ko);
    bf16x8 bg[2], bu[2];
    #pragma unroll
    for (int nst = 0; nst < 2; nst++) {
      bg[nst] = *(const bf16x8*)(wg0 + (size_t)(nst * 16) * Kd + ko);
      bu[nst] = *(const bf16x8*)(wu0 + (size_t)(nst * 16) * Kd + ko);
    }
    #pragma unroll
    for (int nst = 0; nst < 2; nst++)
      #pragma unroll
      for (int mt = 0; mt < 4; mt++) {
        accg[nst][mt] = __builtin_amdgcn_mfma_f32_16x16x32_bf16(a[mt], bg[nst], accg[nst][mt], 0, 0, 0);
        accu[nst][mt] = __builtin_amdgcn_mfma_f32_16x16x32_bf16(a[mt], bu[nst], accu[nst][mt], 0, 0, 0);
      }
  }

  const int outRow0 = (MOE ? e * CAP : 0) + m0;
  #pragma unroll
  for (int mt = 0; mt < 4; mt++) {
    #pragma unroll
    for (int reg = 0; reg < 4; reg++) {
      int lr = mt * 16 + quad * 4 + reg;   // C/D: row=quad*4+reg, col=l16
      if (MOE && (m0 + lr) >= count) continue;
      float wt = MOE ? wlist[m0 + lr] : 1.f;
      size_t orow = (size_t)(outRow0 + lr) * outLd;
      #pragma unroll
      for (int nst = 0; nst < 2; nst++) {
        float g = accg[nst][mt][reg];
        float u = accu[nst][mt][reg];
        float hval = (g / (1.f + __expf(-g))) * u * wt;
        Out[orow + ncol + nst * 16 + l16] = f2bf(hval);
      }
    }
  }
}

// ---------------- down-projection GEMM (B = WdT [H][Kd], bf16) ----------------
template<int MOE>
__global__ __launch_bounds__(256) void down_kernel(
    const short* __restrict__ Ab, const short* __restrict__ WdT,
    float* __restrict__ Out, const int* __restrict__ tokens,
    const int* __restrict__ cnt, int Kd)
{
  const int e  = blockIdx.z;
  const int m0 = blockIdx.y * 64;
  const int n0 = blockIdx.x * 128;
  int count = 1 << 30;
  const int* tlist = tokens;
  if (MOE) {
    int c = cnt[e]; if (c > CAP) c = CAP;
    count = c;
    if (m0 >= count) return;
    tlist = tokens + e * CAP;
  }
  const int lane = threadIdx.x & 63;
  const int wave = threadIdx.x >> 6;
  const int quad = lane >> 4;
  const int l16  = lane & 15;
  const int ncol = n0 + wave * 32;

  const short* wd0 = WdT + (MOE ? (size_t)e * Kd * H_DIM : 0)
                         + (size_t)(ncol + l16) * Kd + quad * 8;
  const short* abase = Ab + (MOE ? (size_t)(e * CAP) * Kd : 0);

  const short* arow[4];
  #pragma unroll
  for (int mt = 0; mt < 4; mt++)
    arow[mt] = abase + (size_t)(m0 + mt * 16 + l16) * Kd + quad * 8;

  f32x4 acc[2][4];
  #pragma unroll
  for (int i = 0; i < 2; i++)
    #pragma unroll
    for (int j = 0; j < 4; j++) acc[i][j] = (f32x4){0.f, 0.f, 0.f, 0.f};

  const int kSteps = Kd >> 5;
  for (int kb = 0; kb < kSteps; kb++) {
    const int ko = kb * 32;
    bf16x8 a[4];
    #pragma unroll
    for (int mt = 0; mt < 4; mt++)
      a[mt] = *(const bf16x8*)(arow[mt] + ko);
    bf16x8 b[2];
    #pragma unroll
    for (int nst = 0; nst < 2; nst++)
      b[nst] = *(const bf16x8*)(wd0 + (size_t)(nst * 16) * Kd + ko);
    #pragma unroll
    for (int nst = 0; nst < 2; nst++)
      #pragma unroll
      for (int mt = 0; mt < 4; mt++)
        acc[nst][mt] = __builtin_amdgcn_mfma_f32_16x16x32_bf16(a[mt], b[nst], acc[nst][mt], 0, 0, 0);
  }

  #pragma unroll
  for (int mt = 0; mt < 4; mt++) {
    #pragma unroll
    for (int reg = 0; reg < 4; reg++) {
      int lr = mt * 16 + quad * 4 + reg;
      if (MOE && (m0 + lr) >= count) continue;
      int trow = MOE ? tlist[m0 + lr] : (m0 + lr);
      float* op = Out + (size_t)trow * H_DIM + ncol + l16;
      #pragma unroll
      for (int nst = 0; nst < 2; nst++) {
        float v = acc[nst][mt][reg];
        if (MOE) atomicAdd(op + nst * 16, v);
        else     op[nst * 16] = v;
      }
    }
  }
}

// ---------------- launch ----------------
extern "C" void kernel_launch(void* const* d_in, const int* in_sizes, int n_in,
                              void* d_out, int out_size, void* d_ws, size_t ws_size,
                              hipStream_t stream) {
  (void)in_sizes; (void)n_in; (void)out_size; (void)ws_size;
  const float* x       = (const float*)d_in[0];
  const float* gate_w  = (const float*)d_in[1];
  const float* gate_b  = (const float*)d_in[2];
  const float* w_gate  = (const float*)d_in[3];
  const float* w_up    = (const float*)d_in[4];
  const float* w_down  = (const float*)d_in[5];
  const float* ws_gate = (const float*)d_in[6];
  const float* ws_up   = (const float*)d_in[7];
  const float* ws_down = (const float*)d_in[8];
  float* out = (float*)d_out;

  char* p = (char*)d_ws;
  auto alloc = [&](size_t bytes) {
    char* r = p; p += (bytes + 255) & ~(size_t)255; return r;
  };
  // ~239 MB total workspace
  float* scores = (float*)alloc((size_t)T_TOK * E_NUM * 4);
  int*   cnt    = (int*)  alloc(E_NUM * 4);
  int*   tokens = (int*)  alloc((size_t)E_NUM * CAP * 4);
  float* wts    = (float*)alloc((size_t)E_NUM * CAP * 4);
  short* xb     = (short*)alloc((size_t)T_TOK * H_DIM * 2);
  short* Hs     = (short*)alloc((size_t)T_TOK * SI_DIM * 2);
  short* Hbuf   = (short*)alloc((size_t)E_NUM * CAP * I_DIM * 2);
  short* wgT    = (short*)alloc((size_t)E_NUM * H_DIM * I_DIM * 2);
  short* wuT    = (short*)alloc((size_t)E_NUM * H_DIM * I_DIM * 2);
  short* wdT    = (short*)alloc((size_t)E_NUM * I_DIM * H_DIM * 2);
  short* wsgT   = (short*)alloc((size_t)H_DIM * SI_DIM * 2);
  short* wsuT   = (short*)alloc((size_t)H_DIM * SI_DIM * 2);
  short* wsdT   = (short*)alloc((size_t)SI_DIM * H_DIM * 2);

  cvt_kernel<<<T_TOK * H_DIM / 1024, 256, 0, stream>>>(x, xb);
  zero_cnt<<<1, 64, 0, stream>>>(cnt);
  router_kernel<<<T_TOK / 4, 256, 0, stream>>>(x, gate_w, scores);
  topk_kernel<<<T_TOK, 64, 0, stream>>>(scores, gate_b, cnt, tokens, wts);

  // weight convert+transpose: fp32 [R,C] -> bf16 [C,R]
  tr_kernel<<<dim3(I_DIM / 32, H_DIM / 32, E_NUM), 256, 0, stream>>>(w_gate, wgT, H_DIM, I_DIM);
  tr_kernel<<<dim3(I_DIM / 32, H_DIM / 32, E_NUM), 256, 0, stream>>>(w_up,   wuT, H_DIM, I_DIM);
  tr_kernel<<<dim3(H_DIM / 32, I_DIM / 32, E_NUM), 256, 0, stream>>>(w_down, wdT, I_DIM, H_DIM);
  tr_kernel<<<dim3(SI_DIM / 32, H_DIM / 32, 1), 256, 0, stream>>>(ws_gate, wsgT, H_DIM, SI_DIM);
  tr_kernel<<<dim3(SI_DIM / 32, H_DIM / 32, 1), 256, 0, stream>>>(ws_up,   wsuT, H_DIM, SI_DIM);
  tr_kernel<<<dim3(H_DIM / 32, SI_DIM / 32, 1), 256, 0, stream>>>(ws_down, wsdT, SI_DIM, H_DIM);

  // shared expert: gate/up -> Hs, then down -> writes out
  gu_kernel<0><<<dim3(SI_DIM / 128, T_TOK / 64, 1), 256, 0, stream>>>(
      xb, wsgT, wsuT, Hs, nullptr, nullptr, nullptr, H_DIM, SI_DIM, SI_DIM);
  // MoE experts: gate/up -> Hbuf (weighted)
  gu_kernel<1><<<dim3(I_DIM / 128, CAP / 64, E_NUM), 256, 0, stream>>>(
      xb, wgT, wuT, Hbuf, tokens, wts, cnt, H_DIM, I_DIM, I_DIM);
  // shared down writes out, then MoE down accumulates atomically
  down_kernel<0><<<dim3(H_DIM / 128, T_TOK / 64, 1), 256, 0, stream>>>(
      Hs, wsdT, out, nullptr, nullptr, SI_DIM);
  down_kernel<1><<<dim3(H_DIM / 128, CAP / 64, E_NUM), 256, 0, stream>>>(
      Hbuf, wdT, out, tokens, cnt, I_DIM);
}

// Round 3
// 804.047 us; speedup vs baseline: 1.1691x; 1.1691x over previous
//
#include <hip/hip_runtime.h>

#define T_TOK 2048
#define H_DIM 1024
#define E_NUM 64
#define TOPK  6
#define I_DIM 512
#define SI_DIM 1024
#define CAP   320   // max tokens/expert supported (avg 192, 9+ sigma headroom)

typedef __attribute__((ext_vector_type(8))) short bf16x8;
typedef __attribute__((ext_vector_type(4))) float f32x4;
typedef __attribute__((ext_vector_type(4))) short short4v;

__device__ __forceinline__ short f2bf(float f) {
  union { float f; unsigned u; } v; v.f = f;
  unsigned r = v.u + 0x7FFFu + ((v.u >> 16) & 1u);  // RNE
  return (short)(r >> 16);
}

__device__ __forceinline__ void gl_lds16(const short* g, short* l) {
  // global (per-lane addr) -> LDS (wave-uniform base + lane*16), 16B/lane
  __builtin_amdgcn_global_load_lds(
      (const __attribute__((address_space(1))) unsigned int*)g,
      (__attribute__((address_space(3))) unsigned int*)l, 16, 0, 0);
}

// ---------------- x -> bf16 ----------------
__global__ __launch_bounds__(256) void cvt_kernel(const float* __restrict__ x,
                                                  short* __restrict__ xb) {
  int i = (blockIdx.x * 256 + threadIdx.x) * 4;
  float4 v = *(const float4*)(x + i);
  short4v o;
  o[0] = f2bf(v.x); o[1] = f2bf(v.y); o[2] = f2bf(v.z); o[3] = f2bf(v.w);
  *(short4v*)(xb + i) = o;
}

// ---------------- weight convert + transpose: fp32 [R,C] -> bf16 [C,R] ----------------
__global__ __launch_bounds__(256) void tr_kernel(const float* __restrict__ in,
                                                 short* __restrict__ outp,
                                                 int R, int C) {
  __shared__ short lds[32][36];
  const size_t off = (size_t)blockIdx.z * R * C;
  const int c0 = blockIdx.x * 32, r0 = blockIdx.y * 32;
  const int tr = threadIdx.x >> 3;
  const int tc = (threadIdx.x & 7) * 4;
  float4 v = *(const float4*)(in + off + (size_t)(r0 + tr) * C + c0 + tc);
  short4v s;
  s[0] = f2bf(v.x); s[1] = f2bf(v.y); s[2] = f2bf(v.z); s[3] = f2bf(v.w);
  *(short4v*)&lds[tr][tc] = s;
  __syncthreads();
  short4v o;
  #pragma unroll
  for (int j = 0; j < 4; j++) o[j] = lds[tc + j][tr];
  *(short4v*)(outp + off + (size_t)(c0 + tr) * R + r0 + tc) = o;
}

__global__ void zero_kernel(int* __restrict__ cnt) {
  if (threadIdx.x < E_NUM + 1) cnt[threadIdx.x] = 0;   // cnt[64] = pair counter
}

// ---------------- router: fp32 exact ----------------
__global__ __launch_bounds__(256) void router_kernel(const float* __restrict__ x,
                                                     const float* __restrict__ gw,
                                                     float* __restrict__ scores) {
  int t = blockIdx.x * 4 + (threadIdx.x >> 6);
  int e = threadIdx.x & 63;
  const float4* xr = (const float4*)(x + (size_t)t * H_DIM);
  const float4* wr = (const float4*)(gw + (size_t)e * H_DIM);
  float s = 0.f;
  #pragma unroll 4
  for (int i = 0; i < H_DIM / 4; i++) {
    float4 a = xr[i], b = wr[i];
    s = fmaf(a.x, b.x, s); s = fmaf(a.y, b.y, s);
    s = fmaf(a.z, b.z, s); s = fmaf(a.w, b.w, s);
  }
  scores[t * E_NUM + e] = 1.f / (1.f + __expf(-s));
}

// ---------------- top-k + routing tables ----------------
__global__ __launch_bounds__(64) void topk_kernel(const float* __restrict__ scores,
                                                  const float* __restrict__ bias,
                                                  int* __restrict__ cnt,
                                                  float* __restrict__ wts,
                                                  int* __restrict__ qmap,
                                                  unsigned* __restrict__ pairs,
                                                  int* __restrict__ dslot) {
  int t = blockIdx.x;
  int e = threadIdx.x;
  float s = scores[t * E_NUM + e];
  float c = s + bias[e];
  int selected = 0;
  float sum = 0.f;
  for (int k = 0; k < TOPK; k++) {
    float v = c; int idx = e;
    #pragma unroll
    for (int off = 32; off > 0; off >>= 1) {
      float v2 = __shfl_xor(v, off);
      int  i2 = __shfl_xor(idx, off);
      if (v2 > v || (v2 == v && i2 < idx)) { v = v2; idx = i2; }
    }
    sum += __shfl(s, idx);
    if (e == idx) { selected = 1; c = -__builtin_inff(); }
  }
  unsigned long long m = __ballot(selected);
  if (selected) {
    int rank = __popcll(m & ((1ull << e) - 1ull));
    int pos = atomicAdd(&cnt[e], 1);
    int qid = atomicAdd(&cnt[E_NUM], 1);
    if (pos >= CAP) pos = CAP - 1;           // ~never; clamp for safety
    int slot = e * CAP + pos;
    wts[slot] = s / sum;
    qmap[slot] = qid;
    pairs[qid] = ((unsigned)t << 16) | (unsigned)slot;
    dslot[t * TOPK + rank] = qid;
  }
}

// ---------------- gather: xb row t -> Xg row slot ----------------
__global__ __launch_bounds__(128) void gather_kernel(const unsigned* __restrict__ pairs,
                                                     const short* __restrict__ xb,
                                                     short* __restrict__ Xg) {
  unsigned pr = pairs[blockIdx.x];
  int t = pr >> 16, slot = pr & 0xFFFF;
  int i = threadIdx.x * 8;
  *(bf16x8*)(Xg + (size_t)slot * H_DIM + i) =
      *(const bf16x8*)(xb + (size_t)t * H_DIM + i);
}

// ---------------- fused gate+up GEMM + SwiGLU (m97-style LDS staging) ----------------
// Tile 128x128, BK=32, 4 waves in 2x2, 4x4 frags/wave, two B matrices.
template<int MOE>
__global__ __launch_bounds__(256) void gemm_gu(
    const short* __restrict__ A, const short* __restrict__ Bg,
    const short* __restrict__ Bu, short* __restrict__ Out,
    const float* __restrict__ wts, const int* __restrict__ cnt,
    int K, int ldOut)
{
  __shared__ short As[128 * 32], Bgs[128 * 32], Bus[128 * 32];
  const int e  = blockIdx.z;
  const int m0 = blockIdx.y * 128;
  const int n0 = blockIdx.x * 128;
  int count = T_TOK;
  const float* wl = wts;
  if (MOE) {
    int c = cnt[e]; if (c > CAP) c = CAP;
    count = c;
    if (m0 >= count) return;
    A   += (size_t)e * CAP * K;
    Bg  += (size_t)e * ldOut * K;
    Bu  += (size_t)e * ldOut * K;
    Out += (size_t)e * CAP * ldOut;
    wl   = wts + e * CAP;
  }
  const int lane = threadIdx.x & 63, wave = threadIdx.x >> 6;
  const int quad = lane >> 4, l16 = lane & 15;
  const int wm = wave >> 1, wn = wave & 1;
  const int srow = lane >> 2, schk = lane & 3;   // staging: 16 rows x 4 chunks per instr

  f32x4 accg[4][4], accu[4][4];
  #pragma unroll
  for (int i = 0; i < 4; i++)
    #pragma unroll
    for (int j = 0; j < 4; j++) {
      accg[i][j] = (f32x4){0.f, 0.f, 0.f, 0.f};
      accu[i][j] = (f32x4){0.f, 0.f, 0.f, 0.f};
    }

  for (int ko = 0; ko < K; ko += 32) {
    __syncthreads();
    #pragma unroll
    for (int i = 0; i < 2; i++) {
      const int rb = wave * 32 + i * 16;
      const int r = rb + srow;
      gl_lds16(A  + (size_t)(m0 + r) * K + ko + schk * 8, &As [rb * 32]);
      gl_lds16(Bg + (size_t)(n0 + r) * K + ko + schk * 8, &Bgs[rb * 32]);
      gl_lds16(Bu + (size_t)(n0 + r) * K + ko + schk * 8, &Bus[rb * 32]);
    }
    __syncthreads();
    bf16x8 a[4], bg[4], bu[4];
    #pragma unroll
    for (int mt = 0; mt < 4; mt++)
      a[mt] = *(const bf16x8*)&As[(wm * 64 + mt * 16 + l16) * 32 + quad * 8];
    #pragma unroll
    for (int nt = 0; nt < 4; nt++) {
      bg[nt] = *(const bf16x8*)&Bgs[(wn * 64 + nt * 16 + l16) * 32 + quad * 8];
      bu[nt] = *(const bf16x8*)&Bus[(wn * 64 + nt * 16 + l16) * 32 + quad * 8];
    }
    #pragma unroll
    for (int mt = 0; mt < 4; mt++)
      #pragma unroll
      for (int nt = 0; nt < 4; nt++) {
        accg[mt][nt] = __builtin_amdgcn_mfma_f32_16x16x32_bf16(a[mt], bg[nt], accg[mt][nt], 0, 0, 0);
        accu[mt][nt] = __builtin_amdgcn_mfma_f32_16x16x32_bf16(a[mt], bu[nt], accu[mt][nt], 0, 0, 0);
      }
  }

  #pragma unroll
  for (int mt = 0; mt < 4; mt++) {
    #pragma unroll
    for (int reg = 0; reg < 4; reg++) {
      int lr = wm * 64 + mt * 16 + quad * 4 + reg;
      int gr = m0 + lr;
      if (MOE && gr >= count) continue;
      float wt = MOE ? wl[gr] : 1.f;
      size_t ro = (size_t)gr * ldOut;
      #pragma unroll
      for (int nt = 0; nt < 4; nt++) {
        int col = n0 + wn * 64 + nt * 16 + l16;
        float g = accg[mt][nt][reg];
        float u = accu[mt][nt][reg];
        Out[ro + col] = f2bf((g / (1.f + __expf(-g))) * u * wt);
      }
    }
  }
}

// ---------------- down-projection GEMM ----------------
// MOE=1: store fp32 rows into Pbuf[qid]; MOE=0: direct store to out.
template<int MOE>
__global__ __launch_bounds__(256) void gemm_down(
    const short* __restrict__ A, const short* __restrict__ Bd,
    float* __restrict__ OutP, const int* __restrict__ qmap,
    const int* __restrict__ cnt, int K)
{
  __shared__ short As[128 * 32], Bs[128 * 32];
  const int e  = blockIdx.z;
  const int m0 = blockIdx.y * 128;
  const int n0 = blockIdx.x * 128;
  int count = T_TOK;
  const int* qm = qmap;
  if (MOE) {
    int c = cnt[e]; if (c > CAP) c = CAP;
    count = c;
    if (m0 >= count) return;
    A  += (size_t)e * CAP * K;
    Bd += (size_t)e * H_DIM * K;
    qm  = qmap + e * CAP;
  }
  const int lane = threadIdx.x & 63, wave = threadIdx.x >> 6;
  const int quad = lane >> 4, l16 = lane & 15;
  const int wm = wave >> 1, wn = wave & 1;
  const int srow = lane >> 2, schk = lane & 3;

  f32x4 acc[4][4];
  #pragma unroll
  for (int i = 0; i < 4; i++)
    #pragma unroll
    for (int j = 0; j < 4; j++) acc[i][j] = (f32x4){0.f, 0.f, 0.f, 0.f};

  for (int ko = 0; ko < K; ko += 32) {
    __syncthreads();
    #pragma unroll
    for (int i = 0; i < 2; i++) {
      const int rb = wave * 32 + i * 16;
      const int r = rb + srow;
      gl_lds16(A  + (size_t)(m0 + r) * K + ko + schk * 8, &As[rb * 32]);
      gl_lds16(Bd + (size_t)(n0 + r) * K + ko + schk * 8, &Bs[rb * 32]);
    }
    __syncthreads();
    bf16x8 a[4], b[4];
    #pragma unroll
    for (int mt = 0; mt < 4; mt++)
      a[mt] = *(const bf16x8*)&As[(wm * 64 + mt * 16 + l16) * 32 + quad * 8];
    #pragma unroll
    for (int nt = 0; nt < 4; nt++)
      b[nt] = *(const bf16x8*)&Bs[(wn * 64 + nt * 16 + l16) * 32 + quad * 8];
    #pragma unroll
    for (int mt = 0; mt < 4; mt++)
      #pragma unroll
      for (int nt = 0; nt < 4; nt++)
        acc[mt][nt] = __builtin_amdgcn_mfma_f32_16x16x32_bf16(a[mt], b[nt], acc[mt][nt], 0, 0, 0);
  }

  #pragma unroll
  for (int mt = 0; mt < 4; mt++) {
    #pragma unroll
    for (int reg = 0; reg < 4; reg++) {
      int lr = wm * 64 + mt * 16 + quad * 4 + reg;
      int gr = m0 + lr;
      if (MOE && gr >= count) continue;
      size_t ro;
      if (MOE) ro = (size_t)qm[gr] * H_DIM;
      else     ro = (size_t)gr * H_DIM;
      #pragma unroll
      for (int nt = 0; nt < 4; nt++) {
        int col = n0 + wn * 64 + nt * 16 + l16;
        OutP[ro + col] = acc[mt][nt][reg];
      }
    }
  }
}

// ---------------- combine: out[t] += sum_k Pbuf[dslot[t][k]] ----------------
__global__ __launch_bounds__(256) void combine_kernel(float* __restrict__ out,
                                                      const float* __restrict__ Pbuf,
                                                      const int* __restrict__ dslot) {
  int t = blockIdx.x;
  int c = threadIdx.x * 4;
  float4 acc = *(float4*)(out + (size_t)t * H_DIM + c);
  #pragma unroll
  for (int k = 0; k < TOPK; k++) {
    int q = dslot[t * TOPK + k];
    float4 p = *(const float4*)(Pbuf + (size_t)q * H_DIM + c);
    acc.x += p.x; acc.y += p.y; acc.z += p.z; acc.w += p.w;
  }
  *(float4*)(out + (size_t)t * H_DIM + c) = acc;
}

// ---------------- launch ----------------
extern "C" void kernel_launch(void* const* d_in, const int* in_sizes, int n_in,
                              void* d_out, int out_size, void* d_ws, size_t ws_size,
                              hipStream_t stream) {
  (void)in_sizes; (void)n_in; (void)out_size; (void)ws_size;
  const float* x       = (const float*)d_in[0];
  const float* gate_w  = (const float*)d_in[1];
  const float* gate_b  = (const float*)d_in[2];
  const float* w_gate  = (const float*)d_in[3];
  const float* w_up    = (const float*)d_in[4];
  const float* w_down  = (const float*)d_in[5];
  const float* ws_gate = (const float*)d_in[6];
  const float* ws_up   = (const float*)d_in[7];
  const float* ws_down = (const float*)d_in[8];
  float* out = (float*)d_out;

  char* p = (char*)d_ws;
  auto alloc = [&](size_t bytes) {
    char* r = p; p += (bytes + 255) & ~(size_t)255; return r;
  };
  float*    scores = (float*)   alloc((size_t)T_TOK * E_NUM * 4);
  int*      cnt    = (int*)     alloc(72 * 4);
  unsigned* pairs  = (unsigned*)alloc((size_t)T_TOK * TOPK * 4);
  float*    wts    = (float*)   alloc((size_t)E_NUM * CAP * 4);
  int*      qmap   = (int*)     alloc((size_t)E_NUM * CAP * 4);
  int*      dslot  = (int*)     alloc((size_t)T_TOK * TOPK * 4);
  short*    xb     = (short*)   alloc((size_t)T_TOK * H_DIM * 2);
  short*    Hs     = (short*)   alloc((size_t)T_TOK * SI_DIM * 2);
  short*    Xg     = (short*)   alloc((size_t)E_NUM * CAP * H_DIM * 2);
  short*    Hbuf   = (short*)   alloc((size_t)E_NUM * CAP * I_DIM * 2);
  short*    wgT    = (short*)   alloc((size_t)E_NUM * H_DIM * I_DIM * 2);   // later: wdT
  short*    wuT    = (short*)   alloc((size_t)E_NUM * H_DIM * I_DIM * 2);   // later: Pbuf
  short*    wsgT   = (short*)   alloc((size_t)H_DIM * SI_DIM * 2);
  short*    wsuT   = (short*)   alloc((size_t)H_DIM * SI_DIM * 2);
  short*    wsdT   = (short*)   alloc((size_t)SI_DIM * H_DIM * 2);
  short*    wdT    = wgT;              // alias: transposed after gu kernels
  float*    Pbuf   = (float*)wuT;      // alias: 12288*1024*4 = 50MB < 64MB

  cvt_kernel<<<T_TOK * H_DIM / 1024, 256, 0, stream>>>(x, xb);
  zero_kernel<<<1, 128, 0, stream>>>(cnt);
  router_kernel<<<T_TOK / 4, 256, 0, stream>>>(x, gate_w, scores);
  topk_kernel<<<T_TOK, 64, 0, stream>>>(scores, gate_b, cnt, wts, qmap, pairs, dslot);
  gather_kernel<<<T_TOK * TOPK, 128, 0, stream>>>(pairs, xb, Xg);

  tr_kernel<<<dim3(SI_DIM / 32, H_DIM / 32, 1), 256, 0, stream>>>(ws_gate, wsgT, H_DIM, SI_DIM);
  tr_kernel<<<dim3(SI_DIM / 32, H_DIM / 32, 1), 256, 0, stream>>>(ws_up,   wsuT, H_DIM, SI_DIM);
  tr_kernel<<<dim3(H_DIM / 32, SI_DIM / 32, 1), 256, 0, stream>>>(ws_down, wsdT, SI_DIM, H_DIM);
  tr_kernel<<<dim3(I_DIM / 32, H_DIM / 32, E_NUM), 256, 0, stream>>>(w_gate, wgT, H_DIM, I_DIM);
  tr_kernel<<<dim3(I_DIM / 32, H_DIM / 32, E_NUM), 256, 0, stream>>>(w_up,   wuT, H_DIM, I_DIM);

  // shared expert gate/up: [2048,1024]x[1024 cols] -> Hs
  gemm_gu<0><<<dim3(SI_DIM / 128, T_TOK / 128, 1), 256, 0, stream>>>(
      xb, wsgT, wsuT, Hs, nullptr, nullptr, H_DIM, SI_DIM);
  // MoE gate/up: per expert -> Hbuf (weighted)
  gemm_gu<1><<<dim3(I_DIM / 128, 3, E_NUM), 256, 0, stream>>>(
      Xg, wgT, wuT, Hbuf, wts, cnt, H_DIM, I_DIM);

  // now wgT free -> transpose w_down into it
  tr_kernel<<<dim3(H_DIM / 32, I_DIM / 32, E_NUM), 256, 0, stream>>>(w_down, wdT, I_DIM, H_DIM);

  // shared down -> writes out
  gemm_down<0><<<dim3(H_DIM / 128, T_TOK / 128, 1), 256, 0, stream>>>(
      Hs, wsdT, out, nullptr, nullptr, SI_DIM);
  // MoE down -> Pbuf rows (wuT region, free after gemm_gu)
  gemm_down<1><<<dim3(H_DIM / 128, 3, E_NUM), 256, 0, stream>>>(
      Hbuf, wdT, Pbuf, qmap, cnt, I_DIM);
  // out += per-token sum of its 6 partial rows
  combine_kernel<<<T_TOK, 256, 0, stream>>>(out, Pbuf, dslot);
}

// Round 4
// 742.974 us; speedup vs baseline: 1.2652x; 1.0822x over previous
//
#include <hip/hip_runtime.h>

#define T_TOK 2048
#define H_DIM 1024
#define E_NUM 64
#define TOPK  6
#define I_DIM 512
#define SI_DIM 1024
#define CAP   320   // max tokens/expert (avg 192; R3 passed at 320 with no clamping)

typedef __attribute__((ext_vector_type(8))) short bf16x8;
typedef __attribute__((ext_vector_type(4))) float f32x4;
typedef __attribute__((ext_vector_type(4))) short short4v;

__device__ __forceinline__ short f2bf(float f) {
  union { float f; unsigned u; } v; v.f = f;
  unsigned r = v.u + 0x7FFFu + ((v.u >> 16) & 1u);  // RNE
  return (short)(r >> 16);
}
__device__ __forceinline__ float bf2f(short s) {
  union { unsigned u; float f; } v;
  v.u = ((unsigned)(unsigned short)s) << 16;
  return v.f;
}

__device__ __forceinline__ void gl_lds16(const short* g, short* l) {
  __builtin_amdgcn_global_load_lds(
      (const __attribute__((address_space(1))) unsigned int*)g,
      (__attribute__((address_space(3))) unsigned int*)l, 16, 0, 0);
}

// ---------------- x -> bf16 ----------------
__global__ __launch_bounds__(256) void cvt_kernel(const float* __restrict__ x,
                                                  short* __restrict__ xb) {
  int i = (blockIdx.x * 256 + threadIdx.x) * 4;
  float4 v = *(const float4*)(x + i);
  short4v o;
  o[0] = f2bf(v.x); o[1] = f2bf(v.y); o[2] = f2bf(v.z); o[3] = f2bf(v.w);
  *(short4v*)(xb + i) = o;
}

// ---------------- weight convert + transpose: fp32 [R,C] -> bf16 [C,R] ----------------
__global__ __launch_bounds__(256) void tr_kernel(const float* __restrict__ in,
                                                 short* __restrict__ outp,
                                                 int R, int C) {
  __shared__ short lds[32][36];
  const size_t off = (size_t)blockIdx.z * R * C;
  const int c0 = blockIdx.x * 32, r0 = blockIdx.y * 32;
  const int tr = threadIdx.x >> 3;
  const int tc = (threadIdx.x & 7) * 4;
  float4 v = *(const float4*)(in + off + (size_t)(r0 + tr) * C + c0 + tc);
  short4v s;
  s[0] = f2bf(v.x); s[1] = f2bf(v.y); s[2] = f2bf(v.z); s[3] = f2bf(v.w);
  *(short4v*)&lds[tr][tc] = s;
  __syncthreads();
  short4v o;
  #pragma unroll
  for (int j = 0; j < 4; j++) o[j] = lds[tc + j][tr];
  *(short4v*)(outp + off + (size_t)(c0 + tr) * R + r0 + tc) = o;
}

__global__ void zero_kernel(int* __restrict__ cnt) {
  if (threadIdx.x < E_NUM + 1) cnt[threadIdx.x] = 0;
}

// ---------------- router: fp32 exact ----------------
__global__ __launch_bounds__(256) void router_kernel(const float* __restrict__ x,
                                                     const float* __restrict__ gw,
                                                     float* __restrict__ scores) {
  int t = blockIdx.x * 4 + (threadIdx.x >> 6);
  int e = threadIdx.x & 63;
  const float4* xr = (const float4*)(x + (size_t)t * H_DIM);
  const float4* wr = (const float4*)(gw + (size_t)e * H_DIM);
  float s = 0.f;
  #pragma unroll 4
  for (int i = 0; i < H_DIM / 4; i++) {
    float4 a = xr[i], b = wr[i];
    s = fmaf(a.x, b.x, s); s = fmaf(a.y, b.y, s);
    s = fmaf(a.z, b.z, s); s = fmaf(a.w, b.w, s);
  }
  scores[t * E_NUM + e] = 1.f / (1.f + __expf(-s));
}

// ---------------- top-k + routing tables ----------------
__global__ __launch_bounds__(64) void topk_kernel(const float* __restrict__ scores,
                                                  const float* __restrict__ bias,
                                                  int* __restrict__ cnt,
                                                  float* __restrict__ wts,
                                                  int* __restrict__ qmap,
                                                  unsigned* __restrict__ pairs,
                                                  int* __restrict__ dslot) {
  int t = blockIdx.x;
  int e = threadIdx.x;
  float s = scores[t * E_NUM + e];
  float c = s + bias[e];
  int selected = 0;
  float sum = 0.f;
  for (int k = 0; k < TOPK; k++) {
    float v = c; int idx = e;
    #pragma unroll
    for (int off = 32; off > 0; off >>= 1) {
      float v2 = __shfl_xor(v, off);
      int  i2 = __shfl_xor(idx, off);
      if (v2 > v || (v2 == v && i2 < idx)) { v = v2; idx = i2; }
    }
    sum += __shfl(s, idx);
    if (e == idx) { selected = 1; c = -__builtin_inff(); }
  }
  unsigned long long m = __ballot(selected);
  if (selected) {
    int rank = __popcll(m & ((1ull << e) - 1ull));
    int pos = atomicAdd(&cnt[e], 1);
    int qid = atomicAdd(&cnt[E_NUM], 1);
    if (pos >= CAP) pos = CAP - 1;
    int slot = e * CAP + pos;         // < 20480, fits 16 bits
    wts[slot] = s / sum;
    qmap[slot] = qid;
    pairs[qid] = ((unsigned)t << 16) | (unsigned)slot;
    dslot[t * TOPK + rank] = qid;
  }
}

// ---------------- gather: xb row t -> Xg row slot ----------------
__global__ __launch_bounds__(128) void gather_kernel(const unsigned* __restrict__ pairs,
                                                     const short* __restrict__ xb,
                                                     short* __restrict__ Xg) {
  unsigned pr = pairs[blockIdx.x];
  int t = pr >> 16, slot = pr & 0xFFFF;
  int i = threadIdx.x * 8;
  *(bf16x8*)(Xg + (size_t)slot * H_DIM + i) =
      *(const bf16x8*)(xb + (size_t)t * H_DIM + i);
}

// ---------------- paired GEMM: C0 = A x B0^T, C1 = A x B1^T (x-dim selects) ----------------
// Tile 128x128, BK=32, 4 waves 2x2, 4x4 frags/wave, LDS 16KB, >=4 blocks/CU.
template<int MOE>
__global__ __launch_bounds__(256, 4) void gemm_pair(
    const short* __restrict__ A, const short* __restrict__ B0,
    const short* __restrict__ B1, short* __restrict__ O0,
    short* __restrict__ O1, const int* __restrict__ cnt,
    int K, int N)
{
  __shared__ short As[128 * 32], Bs[128 * 32];
  const int half = N >> 7;
  int bx = blockIdx.x;
  const short* B = B0; short* O = O0;
  if (bx >= half) { B = B1; O = O1; bx -= half; }
  const int e  = blockIdx.z;
  const int m0 = blockIdx.y * 128;
  const int n0 = bx * 128;
  int count = T_TOK;
  if (MOE) {
    int c = cnt[e]; if (c > CAP) c = CAP;
    count = c;
    if (m0 >= count) return;
    A += (size_t)e * CAP * K;
    B += (size_t)e * N * K;
    O += (size_t)e * CAP * N;
  }
  const int lane = threadIdx.x & 63, wave = threadIdx.x >> 6;
  const int quad = lane >> 4, l16 = lane & 15;
  const int wm = wave >> 1, wn = wave & 1;
  const int srow = lane >> 2, schk = lane & 3;

  f32x4 acc[4][4];
  #pragma unroll
  for (int i = 0; i < 4; i++)
    #pragma unroll
    for (int j = 0; j < 4; j++) acc[i][j] = (f32x4){0.f, 0.f, 0.f, 0.f};

  for (int ko = 0; ko < K; ko += 32) {
    __syncthreads();
    #pragma unroll
    for (int i = 0; i < 2; i++) {
      const int rb = wave * 32 + i * 16;
      const int r = rb + srow;
      gl_lds16(A + (size_t)(m0 + r) * K + ko + schk * 8, &As[rb * 32]);
      gl_lds16(B + (size_t)(n0 + r) * K + ko + schk * 8, &Bs[rb * 32]);
    }
    __syncthreads();
    bf16x8 a[4], b[4];
    #pragma unroll
    for (int mt = 0; mt < 4; mt++)
      a[mt] = *(const bf16x8*)&As[(wm * 64 + mt * 16 + l16) * 32 + quad * 8];
    #pragma unroll
    for (int nt = 0; nt < 4; nt++)
      b[nt] = *(const bf16x8*)&Bs[(wn * 64 + nt * 16 + l16) * 32 + quad * 8];
    #pragma unroll
    for (int mt = 0; mt < 4; mt++)
      #pragma unroll
      for (int nt = 0; nt < 4; nt++)
        acc[mt][nt] = __builtin_amdgcn_mfma_f32_16x16x32_bf16(a[mt], b[nt], acc[mt][nt], 0, 0, 0);
  }

  #pragma unroll
  for (int mt = 0; mt < 4; mt++) {
    #pragma unroll
    for (int reg = 0; reg < 4; reg++) {
      int gr = m0 + wm * 64 + mt * 16 + quad * 4 + reg;
      if (MOE && gr >= count) continue;
      size_t ro = (size_t)gr * N;
      #pragma unroll
      for (int nt = 0; nt < 4; nt++)
        O[ro + n0 + wn * 64 + nt * 16 + l16] = f2bf(acc[mt][nt][reg]);
    }
  }
}

// ---------------- SwiGLU elementwise ----------------
__global__ __launch_bounds__(256) void swiglu_moe(const unsigned* __restrict__ pairs,
                                                  const short* __restrict__ G,
                                                  const short* __restrict__ U,
                                                  const float* __restrict__ wts,
                                                  short* __restrict__ H) {
  int qid = blockIdx.x * 4 + (threadIdx.x >> 6);
  unsigned pr = pairs[qid];
  int slot = pr & 0xFFFF;
  float wt = wts[slot];
  int i = (threadIdx.x & 63) * 8;
  bf16x8 g8 = *(const bf16x8*)(G + (size_t)slot * I_DIM + i);
  bf16x8 u8 = *(const bf16x8*)(U + (size_t)slot * I_DIM + i);
  bf16x8 o;
  #pragma unroll
  for (int j = 0; j < 8; j++) {
    float g = bf2f(g8[j]), u = bf2f(u8[j]);
    o[j] = f2bf((g / (1.f + __expf(-g))) * u * wt);
  }
  *(bf16x8*)(H + (size_t)slot * I_DIM + i) = o;
}

__global__ __launch_bounds__(256) void swiglu_shared(const short* __restrict__ G,
                                                     const short* __restrict__ U,
                                                     short* __restrict__ H) {
  size_t i = ((size_t)blockIdx.x * 256 + threadIdx.x) * 8;
  bf16x8 g8 = *(const bf16x8*)(G + i);
  bf16x8 u8 = *(const bf16x8*)(U + i);
  bf16x8 o;
  #pragma unroll
  for (int j = 0; j < 8; j++) {
    float g = bf2f(g8[j]), u = bf2f(u8[j]);
    o[j] = f2bf((g / (1.f + __expf(-g))) * u);
  }
  *(bf16x8*)(H + i) = o;
}

// ---------------- down-projection GEMM ----------------
template<int MOE>
__global__ __launch_bounds__(256, 4) void gemm_down(
    const short* __restrict__ A, const short* __restrict__ Bd,
    float* __restrict__ OutP, const int* __restrict__ qmap,
    const int* __restrict__ cnt, int K)
{
  __shared__ short As[128 * 32], Bs[128 * 32];
  const int e  = blockIdx.z;
  const int m0 = blockIdx.y * 128;
  const int n0 = blockIdx.x * 128;
  int count = T_TOK;
  const int* qm = qmap;
  if (MOE) {
    int c = cnt[e]; if (c > CAP) c = CAP;
    count = c;
    if (m0 >= count) return;
    A  += (size_t)e * CAP * K;
    Bd += (size_t)e * H_DIM * K;
    qm  = qmap + e * CAP;
  }
  const int lane = threadIdx.x & 63, wave = threadIdx.x >> 6;
  const int quad = lane >> 4, l16 = lane & 15;
  const int wm = wave >> 1, wn = wave & 1;
  const int srow = lane >> 2, schk = lane & 3;

  f32x4 acc[4][4];
  #pragma unroll
  for (int i = 0; i < 4; i++)
    #pragma unroll
    for (int j = 0; j < 4; j++) acc[i][j] = (f32x4){0.f, 0.f, 0.f, 0.f};

  for (int ko = 0; ko < K; ko += 32) {
    __syncthreads();
    #pragma unroll
    for (int i = 0; i < 2; i++) {
      const int rb = wave * 32 + i * 16;
      const int r = rb + srow;
      gl_lds16(A  + (size_t)(m0 + r) * K + ko + schk * 8, &As[rb * 32]);
      gl_lds16(Bd + (size_t)(n0 + r) * K + ko + schk * 8, &Bs[rb * 32]);
    }
    __syncthreads();
    bf16x8 a[4], b[4];
    #pragma unroll
    for (int mt = 0; mt < 4; mt++)
      a[mt] = *(const bf16x8*)&As[(wm * 64 + mt * 16 + l16) * 32 + quad * 8];
    #pragma unroll
    for (int nt = 0; nt < 4; nt++)
      b[nt] = *(const bf16x8*)&Bs[(wn * 64 + nt * 16 + l16) * 32 + quad * 8];
    #pragma unroll
    for (int mt = 0; mt < 4; mt++)
      #pragma unroll
      for (int nt = 0; nt < 4; nt++)
        acc[mt][nt] = __builtin_amdgcn_mfma_f32_16x16x32_bf16(a[mt], b[nt], acc[mt][nt], 0, 0, 0);
  }

  #pragma unroll
  for (int mt = 0; mt < 4; mt++) {
    #pragma unroll
    for (int reg = 0; reg < 4; reg++) {
      int gr = m0 + wm * 64 + mt * 16 + quad * 4 + reg;
      if (MOE && gr >= count) continue;
      size_t ro = MOE ? (size_t)qm[gr] * H_DIM : (size_t)gr * H_DIM;
      #pragma unroll
      for (int nt = 0; nt < 4; nt++)
        OutP[ro + n0 + wn * 64 + nt * 16 + l16] = acc[mt][nt][reg];
    }
  }
}

// ---------------- combine: out[t] += sum_k Pbuf[dslot[t][k]] ----------------
__global__ __launch_bounds__(256) void combine_kernel(float* __restrict__ out,
                                                      const float* __restrict__ Pbuf,
                                                      const int* __restrict__ dslot) {
  int t = blockIdx.x;
  int c = threadIdx.x * 4;
  float4 acc = *(float4*)(out + (size_t)t * H_DIM + c);
  #pragma unroll
  for (int k = 0; k < TOPK; k++) {
    int q = dslot[t * TOPK + k];
    float4 p = *(const float4*)(Pbuf + (size_t)q * H_DIM + c);
    acc.x += p.x; acc.y += p.y; acc.z += p.z; acc.w += p.w;
  }
  *(float4*)(out + (size_t)t * H_DIM + c) = acc;
}

// ---------------- launch ----------------
extern "C" void kernel_launch(void* const* d_in, const int* in_sizes, int n_in,
                              void* d_out, int out_size, void* d_ws, size_t ws_size,
                              hipStream_t stream) {
  (void)in_sizes; (void)n_in; (void)out_size; (void)ws_size;
  const float* x       = (const float*)d_in[0];
  const float* gate_w  = (const float*)d_in[1];
  const float* gate_b  = (const float*)d_in[2];
  const float* w_gate  = (const float*)d_in[3];
  const float* w_up    = (const float*)d_in[4];
  const float* w_down  = (const float*)d_in[5];
  const float* ws_gate = (const float*)d_in[6];
  const float* ws_up   = (const float*)d_in[7];
  const float* ws_down = (const float*)d_in[8];
  float* out = (float*)d_out;

  // ---- static workspace layout with lifetime-based aliasing (peak ~229 MB) ----
  char* base = (char*)d_ws;
  size_t off = 0;
  auto alloc = [&](size_t bytes) {
    char* r = base + off; off += (bytes + 255) & ~(size_t)255; return r;
  };
  float*    scores = (float*)   alloc((size_t)T_TOK * E_NUM * 4);
  int*      cnt    = (int*)     alloc(72 * 4);
  unsigned* pairs  = (unsigned*)alloc((size_t)T_TOK * TOPK * 4);
  float*    wts    = (float*)   alloc((size_t)E_NUM * CAP * 4);
  int*      qmap   = (int*)     alloc((size_t)E_NUM * CAP * 4);
  int*      dslot  = (int*)     alloc((size_t)T_TOK * TOPK * 4);
  short*    xb     = (short*)   alloc((size_t)T_TOK * H_DIM * 2);
  // region1: Xg (phase 1) -> Hbuf (phase 2)
  char*     reg1   = alloc((size_t)E_NUM * CAP * H_DIM * 2);
  // region2: wgT -> wdT ; region3: wuT -> Pbuf
  char*     reg2   = alloc((size_t)E_NUM * H_DIM * I_DIM * 2);
  char*     reg3   = alloc((size_t)E_NUM * H_DIM * I_DIM * 2);
  // region4: [Gs + wsgT + wsuT] (shared phase) -> Gm (moe phase)
  char*     reg4   = alloc((size_t)E_NUM * CAP * I_DIM * 2);
  // region5: [Us] -> Um
  char*     reg5   = alloc((size_t)E_NUM * CAP * I_DIM * 2);
  short*    Hs     = (short*)   alloc((size_t)T_TOK * SI_DIM * 2);
  short*    wsdT   = (short*)   alloc((size_t)SI_DIM * H_DIM * 2);

  short* Xg   = (short*)reg1;
  short* Hbuf = (short*)reg1;
  short* wgT  = (short*)reg2;
  short* wdT  = (short*)reg2;
  short* wuT  = (short*)reg3;
  float* Pbuf = (float*)reg3;
  short* Gs   = (short*)reg4;
  short* wsgT = (short*)(reg4 + (size_t)T_TOK * SI_DIM * 2);
  short* wsuT = (short*)(reg4 + (size_t)T_TOK * SI_DIM * 2 + (size_t)H_DIM * SI_DIM * 2);
  short* Gm   = (short*)reg4;
  short* Us   = (short*)reg5;
  short* Um   = (short*)reg5;

  // ---- routing ----
  cvt_kernel<<<T_TOK * H_DIM / 1024, 256, 0, stream>>>(x, xb);
  zero_kernel<<<1, 128, 0, stream>>>(cnt);
  router_kernel<<<T_TOK / 4, 256, 0, stream>>>(x, gate_w, scores);
  topk_kernel<<<T_TOK, 64, 0, stream>>>(scores, gate_b, cnt, wts, qmap, pairs, dslot);
  gather_kernel<<<T_TOK * TOPK, 128, 0, stream>>>(pairs, xb, Xg);

  // ---- shared expert phase ----
  tr_kernel<<<dim3(SI_DIM / 32, H_DIM / 32, 1), 256, 0, stream>>>(ws_gate, wsgT, H_DIM, SI_DIM);
  tr_kernel<<<dim3(SI_DIM / 32, H_DIM / 32, 1), 256, 0, stream>>>(ws_up,   wsuT, H_DIM, SI_DIM);
  tr_kernel<<<dim3(H_DIM / 32, SI_DIM / 32, 1), 256, 0, stream>>>(ws_down, wsdT, SI_DIM, H_DIM);
  gemm_pair<0><<<dim3(2 * SI_DIM / 128, T_TOK / 128, 1), 256, 0, stream>>>(
      xb, wsgT, wsuT, Gs, Us, nullptr, H_DIM, SI_DIM);
  swiglu_shared<<<T_TOK * SI_DIM / 2048, 256, 0, stream>>>(Gs, Us, Hs);

  // ---- MoE gate/up phase (reg4/reg5 now become Gm/Um) ----
  tr_kernel<<<dim3(I_DIM / 32, H_DIM / 32, E_NUM), 256, 0, stream>>>(w_gate, wgT, H_DIM, I_DIM);
  tr_kernel<<<dim3(I_DIM / 32, H_DIM / 32, E_NUM), 256, 0, stream>>>(w_up,   wuT, H_DIM, I_DIM);
  gemm_pair<1><<<dim3(2 * I_DIM / 128, 3, E_NUM), 256, 0, stream>>>(
      Xg, wgT, wuT, Gm, Um, cnt, H_DIM, I_DIM);
  swiglu_moe<<<T_TOK * TOPK / 4, 256, 0, stream>>>(pairs, Gm, Um, wts, Hbuf);

  // ---- down phase (wgT region -> wdT; wuT region -> Pbuf) ----
  tr_kernel<<<dim3(H_DIM / 32, I_DIM / 32, E_NUM), 256, 0, stream>>>(w_down, wdT, I_DIM, H_DIM);
  gemm_down<0><<<dim3(H_DIM / 128, T_TOK / 128, 1), 256, 0, stream>>>(
      Hs, wsdT, out, nullptr, nullptr, SI_DIM);
  gemm_down<1><<<dim3(H_DIM / 128, 3, E_NUM), 256, 0, stream>>>(
      Hbuf, wdT, Pbuf, qmap, cnt, I_DIM);
  combine_kernel<<<T_TOK, 256, 0, stream>>>(out, Pbuf, dslot);
}